// Round 11
// baseline (218.428 us; speedup 1.0000x reference)
//
#include <hip/hip_runtime.h>
#include <hip/hip_bf16.h>

typedef __bf16 bf16;
typedef __attribute__((ext_vector_type(8))) __bf16 bf16x8;
typedef __attribute__((ext_vector_type(4))) float f32x4;

#define MFMA16(a, b, c) __builtin_amdgcn_mfma_f32_16x16x32_bf16((a), (b), (c), 0, 0, 0)

// B=2, S=2048, D=512, H=8, hd=64, G=4. All I/O float32; bf16 MFMA compute.
static constexpr float EPS = 1e-5f;
static constexpr float LAMBDA_INIT = 0.2f;

// Load 8 consecutive f32 (32B, 16B-aligned) and convert to bf16x8.
__device__ __forceinline__ bf16x8 cvt8(const float* p) {
    const f32x4 a = *(const f32x4*)p;
    const f32x4 b = *(const f32x4*)(p + 4);
    bf16x8 r;
    r[0] = (bf16)a[0]; r[1] = (bf16)a[1]; r[2] = (bf16)a[2]; r[3] = (bf16)a[3];
    r[4] = (bf16)b[0]; r[5] = (bf16)b[1]; r[6] = (bf16)b[2]; r[7] = (bf16)b[3];
    return r;
}

// Async 16B global -> LDS (lane i lands at lds_base + i*16; base wave-uniform).
__device__ __forceinline__ void gload_lds16(const void* g, void* l) {
    __builtin_amdgcn_global_load_lds(
        (const __attribute__((address_space(1))) unsigned int*)g,
        (__attribute__((address_space(3))) unsigned int*)l,
        16, 0, 0);
}

// ---------------------------------------------------------------------------
// Kernel 1: fused QKV projection GEMM (f32 in -> bf16 out), m97-style.
// [unchanged from round 10]
// ---------------------------------------------------------------------------
__global__ __launch_bounds__(256) void proj_kernel(
    const float* __restrict__ x,
    const float* __restrict__ q1w, const float* __restrict__ k1w,
    const float* __restrict__ q2w, const float* __restrict__ k2w,
    const float* __restrict__ vw,
    const float* __restrict__ k1b, const float* __restrict__ k2b,
    bf16* __restrict__ q1o, bf16* __restrict__ k1o,
    bf16* __restrict__ q2o, bf16* __restrict__ k2o,
    bf16* __restrict__ vto)
{
    __shared__ __align__(16) float As[128 * 32];   // 16 KB
    __shared__ __align__(16) float Bs[128 * 32];   // 16 KB

    const int tid = threadIdx.x;
    const int wave = tid >> 6, lane = tid & 63;
    const int l15 = lane & 15, quad = lane >> 4;
    const int wm = wave >> 1, wn = wave & 1;

    const int mb = blockIdx.x / 20;
    const int nb = blockIdx.x % 20;
    const int wsel = nb >> 2;
    const int nrow0 = (nb & 3) * 128;

    const float* W = (wsel == 0) ? q1w : (wsel == 1) ? k1w :
                     (wsel == 2) ? q2w : (wsel == 3) ? k2w : vw;

    const int srow = lane >> 3;
    const int scol = (lane & 7) * 4;
    const float* xg = x + (size_t)(mb * 128 + srow) * 512 + scol;
    const float* wg = W + (size_t)(nrow0 + srow) * 512 + scol;

    f32x4 acc[4][4];
#pragma unroll
    for (int i = 0; i < 4; ++i)
#pragma unroll
        for (int j = 0; j < 4; ++j)
            acc[i][j] = (f32x4){0.f, 0.f, 0.f, 0.f};

    for (int k0 = 0; k0 < 512; k0 += 32) {
#pragma unroll
        for (int c = 0; c < 4; ++c) {
            const int chunk = wave * 4 + c;
            gload_lds16(xg + (size_t)(chunk * 8) * 512 + k0, As + chunk * 256);
            gload_lds16(wg + (size_t)(chunk * 8) * 512 + k0, Bs + chunk * 256);
        }
        __syncthreads();

        bf16x8 af[4], bfr[4];
#pragma unroll
        for (int i = 0; i < 4; ++i)
            af[i] = cvt8(As + (wm * 64 + i * 16 + l15) * 32 + quad * 8);
#pragma unroll
        for (int j = 0; j < 4; ++j)
            bfr[j] = cvt8(Bs + (wn * 64 + j * 16 + l15) * 32 + quad * 8);

#pragma unroll
        for (int i = 0; i < 4; ++i)
#pragma unroll
            for (int j = 0; j < 4; ++j)
                acc[i][j] = MFMA16(af[i], bfr[j], acc[i][j]);

        __syncthreads();
    }

    const float scale = (wsel == 0 || wsel == 2) ? 0.125f : 1.0f;
#pragma unroll
    for (int j = 0; j < 4; ++j) {
        const int ncol = nrow0 + wn * 64 + j * 16 + l15;
        float bias = 0.f;
        if (wsel == 1) bias = k1b[ncol];
        if (wsel == 3) bias = k2b[ncol];
        const int h = ncol >> 6, hd = ncol & 63;
#pragma unroll
        for (int i = 0; i < 4; ++i) {
#pragma unroll
            for (int r = 0; r < 4; ++r) {
                const int m = mb * 128 + wm * 64 + i * 16 + quad * 4 + r;
                const int bidx = m >> 11, s = m & 2047;
                const float v = acc[i][j][r] * scale + bias;
                if (wsel == 4) {
                    const int s5 = s & 31;
                    const int p = ((s5 & 15) >> 2) * 8 + (s5 & 3) + ((s5 >> 4) << 2);
                    const int sp = (s & ~31) | p;
                    vto[((size_t)(bidx * 8 + h) * 64 + hd) * 2048 + sp] = (bf16)v;
                } else {
                    bf16* dst = (wsel == 0) ? q1o : (wsel == 1) ? k1o :
                                (wsel == 2) ? q2o : k2o;
                    dst[((size_t)(bidx * 8 + h) * 2048 + s) * 64 + hd] = (bf16)v;
                }
            }
        }
    }
}

// ---------------------------------------------------------------------------
// Kernel 2: dual-stream flash attention, LDS-read-amortized tiling.
// Block = 8 waves / 64 queries; wave w -> q-half (w>>2: 2 q-tiles = 32 q),
// key-quarter (w&3: 512 keys). Per iter: block stages 128 keys of K1|K2|V
// (48 KB) via global_load_lds; each wave: 12 ds_read_b128 -> 32 MFMA
// (2 q-tiles share the K/V fragments). 4-way cross-quarter (O,l) reduction
// through the 64 KB smem union; fused GroupNorm partial stats.
// Grid = B*H*32 = 512 blocks.
// ---------------------------------------------------------------------------
__global__ __launch_bounds__(512, 2) void attn_kernel(
    const bf16* __restrict__ q1, const bf16* __restrict__ k1,
    const bf16* __restrict__ q2, const bf16* __restrict__ k2,
    const bf16* __restrict__ vt,
    const float* __restrict__ lq1, const float* __restrict__ lk1,
    const float* __restrict__ lq2, const float* __restrict__ lk2,
    bf16* __restrict__ o, float* __restrict__ stats)
{
    __shared__ __align__(16) bf16 smem[32768];   // 64 KB: staging 48 KB / reduce 64 KB
    __shared__ float lbuf[8][2][2][16];          // [wave][stream][qtile][query]
    __shared__ float sred[2][2];

    const int tid = threadIdx.x;
    const int wave = tid >> 6;
    const int lane = tid & 63;
    const int l15 = lane & 15, quad = lane >> 4;
    const int qh = wave >> 2;          // query half (2 q-tiles)
    const int kq = wave & 3;           // key quarter

    const int bh = blockIdx.x >> 5;
    const int qt = blockIdx.x & 31;
    const int b = bh >> 3, h = bh & 7;

    const bf16* k1t = k1 + (size_t)bh * 2048 * 64;
    const bf16* k2t = k2 + (size_t)bh * 2048 * 64;
    const bf16* vtt = vt + (size_t)bh * 64 * 2048;

    // Q fragments for this wave's 2 q-tiles (B-operand: lane = query).
    bf16x8 q1f0[2], q1f1[2], q2f0[2], q2f1[2];
#pragma unroll
    for (int t = 0; t < 2; ++t) {
        const int qrow = qt * 64 + (qh * 2 + t) * 16 + l15;
        const bf16* q1p = q1 + ((size_t)bh * 2048 + qrow) * 64 + quad * 8;
        const bf16* q2p = q2 + ((size_t)bh * 2048 + qrow) * 64 + quad * 8;
        q1f0[t] = *(const bf16x8*)(q1p);
        q1f1[t] = *(const bf16x8*)(q1p + 32);
        q2f0[t] = *(const bf16x8*)(q2p);
        q2f1[t] = *(const bf16x8*)(q2p + 32);
    }

    // Staging: 48 x 1KB calls per iter (K1 16 | K2 16 | V 16); wave does 6.
    // K swizzled: LDS (key,d) at key*64 + (d ^ (key&7)*8). V keeps the
    // period-32 permutation from proj (chunks stay 32-aligned).
    const bf16* gsrc[6]; bf16* ldst[6]; int gstep[6];
#pragma unroll
    for (int j = 0; j < 6; ++j) {
        const int c = wave * 6 + j;
        if (c < 16) {
            gsrc[j] = k1t + (size_t)(c * 8 + (lane >> 3)) * 64
                    + 8 * ((lane & 7) ^ (lane >> 3));
            ldst[j] = smem + c * 512;
            gstep[j] = 128 * 64;
        } else if (c < 32) {
            const int i = c - 16;
            gsrc[j] = k2t + (size_t)(i * 8 + (lane >> 3)) * 64
                    + 8 * ((lane & 7) ^ (lane >> 3));
            ldst[j] = smem + 8192 + i * 512;
            gstep[j] = 128 * 64;
        } else {
            const int i = c - 32;
            gsrc[j] = vtt + (size_t)((i & 3) * 16 + (lane >> 2)) * 2048
                    + (i >> 2) * 32 + (lane & 3) * 8;
            ldst[j] = smem + 16384 + i * 512;
            gstep[j] = 128;
        }
    }

    const bf16* k1r = smem + kq * 2048;
    const bf16* k2r = smem + 8192 + kq * 2048;
    const bf16* vr  = smem + 16384 + kq * 2048;
    const int koffa = 8 * (quad ^ (l15 & 7));
    const int koffb = 8 * ((quad + 4) ^ (l15 & 7));

    f32x4 O1[2][4], O2[2][4];
    float l1[2] = {0.f, 0.f}, l2[2] = {0.f, 0.f};
#pragma unroll
    for (int t = 0; t < 2; ++t)
#pragma unroll
        for (int r = 0; r < 4; ++r) {
            O1[t][r] = (f32x4){0.f, 0.f, 0.f, 0.f};
            O2[t][r] = (f32x4){0.f, 0.f, 0.f, 0.f};
        }

    for (int it = 0; it < 16; ++it) {
#pragma unroll
        for (int j = 0; j < 6; ++j)
            gload_lds16(gsrc[j] + (size_t)it * gstep[j], ldst[j]);
        __syncthreads();   // drains vmcnt: staged data visible

        const bf16x8 k1t0a = *(const bf16x8*)(k1r + l15 * 64 + koffa);
        const bf16x8 k1t0b = *(const bf16x8*)(k1r + l15 * 64 + koffb);
        const bf16x8 k1t1a = *(const bf16x8*)(k1r + (16 + l15) * 64 + koffa);
        const bf16x8 k1t1b = *(const bf16x8*)(k1r + (16 + l15) * 64 + koffb);
        const bf16x8 k2t0a = *(const bf16x8*)(k2r + l15 * 64 + koffa);
        const bf16x8 k2t0b = *(const bf16x8*)(k2r + l15 * 64 + koffb);
        const bf16x8 k2t1a = *(const bf16x8*)(k2r + (16 + l15) * 64 + koffa);
        const bf16x8 k2t1b = *(const bf16x8*)(k2r + (16 + l15) * 64 + koffb);
        const bf16x8 v0 = *(const bf16x8*)(vr + l15 * 32 + quad * 8);
        const bf16x8 v1 = *(const bf16x8*)(vr + (16 + l15) * 32 + quad * 8);
        const bf16x8 v2 = *(const bf16x8*)(vr + (32 + l15) * 32 + quad * 8);
        const bf16x8 v3 = *(const bf16x8*)(vr + (48 + l15) * 32 + quad * 8);

#pragma unroll
        for (int t = 0; t < 2; ++t) {
            f32x4 z = (f32x4){0.f, 0.f, 0.f, 0.f};
            f32x4 s1t0 = MFMA16(k1t0a, q1f0[t], z);  s1t0 = MFMA16(k1t0b, q1f1[t], s1t0);
            f32x4 s1t1 = MFMA16(k1t1a, q1f0[t], z);  s1t1 = MFMA16(k1t1b, q1f1[t], s1t1);
            f32x4 s2t0 = MFMA16(k2t0a, q2f0[t], z);  s2t0 = MFMA16(k2t0b, q2f1[t], s2t0);
            f32x4 s2t1 = MFMA16(k2t1a, q2f0[t], z);  s2t1 = MFMA16(k2t1b, q2f1[t], s2t1);

            bf16x8 b1, b2;
#pragma unroll
            for (int r = 0; r < 4; ++r) {
                float e;
                e = __expf(s1t0[r]); l1[t] += e; b1[r]     = (bf16)e;
                e = __expf(s1t1[r]); l1[t] += e; b1[4 + r] = (bf16)e;
                e = __expf(s2t0[r]); l2[t] += e; b2[r]     = (bf16)e;
                e = __expf(s2t1[r]); l2[t] += e; b2[4 + r] = (bf16)e;
            }

            O1[t][0] = MFMA16(v0, b1, O1[t][0]);
            O1[t][1] = MFMA16(v1, b1, O1[t][1]);
            O1[t][2] = MFMA16(v2, b1, O1[t][2]);
            O1[t][3] = MFMA16(v3, b1, O1[t][3]);
            O2[t][0] = MFMA16(v0, b2, O2[t][0]);
            O2[t][1] = MFMA16(v1, b2, O2[t][1]);
            O2[t][2] = MFMA16(v2, b2, O2[t][2]);
            O2[t][3] = MFMA16(v3, b2, O2[t][3]);
        }

        __syncthreads();   // before next iter overwrites staging
    }

    // Per-wave l: sum over the 4 quads covering this wave's keys.
#pragma unroll
    for (int t = 0; t < 2; ++t) {
        l1[t] += __shfl_xor(l1[t], 16, 64);  l1[t] += __shfl_xor(l1[t], 32, 64);
        l2[t] += __shfl_xor(l2[t], 16, 64);  l2[t] += __shfl_xor(l2[t], 32, 64);
    }
    if (lane < 16) {
        lbuf[wave][0][0][lane] = l1[0];  lbuf[wave][0][1][lane] = l1[1];
        lbuf[wave][1][0][lane] = l2[0];  lbuf[wave][1][1][lane] = l2[1];
    }

    // 4-way cross-quarter O reduction within groups {0..3},{4..7}.
    f32x4* rb = (f32x4*)smem;            // 4096 f32x4 slots (64 KB)
    if (kq & 1) {                        // writers: waves 1,3,5,7
        f32x4* dst = rb + (wave >> 1) * 1024;
#pragma unroll
        for (int t = 0; t < 2; ++t)
#pragma unroll
            for (int r = 0; r < 4; ++r) {
                dst[(t * 8 + r) * 64 + lane]     = O1[t][r];
                dst[(t * 8 + 4 + r) * 64 + lane] = O2[t][r];
            }
    }
    __syncthreads();
    if (!(kq & 1)) {                     // readers: waves 0,2,4,6
        const f32x4* src = rb + (wave >> 1) * 1024;
#pragma unroll
        for (int t = 0; t < 2; ++t)
#pragma unroll
            for (int r = 0; r < 4; ++r) {
                O1[t][r] += src[(t * 8 + r) * 64 + lane];
                O2[t][r] += src[(t * 8 + 4 + r) * 64 + lane];
            }
    }
    __syncthreads();
    if (kq == 2) {                       // writers: waves 2,6
        f32x4* dst = rb + (wave >> 2) * 1024;
#pragma unroll
        for (int t = 0; t < 2; ++t)
#pragma unroll
            for (int r = 0; r < 4; ++r) {
                dst[(t * 8 + r) * 64 + lane]     = O1[t][r];
                dst[(t * 8 + 4 + r) * 64 + lane] = O2[t][r];
            }
    }
    __syncthreads();

    float ssum = 0.f, ssq = 0.f;
    if (kq == 0) {                       // finalizers: waves 0,4
        const f32x4* src = rb + (wave >> 2) * 1024;
        const float lam = __expf(lq1[h] * lk1[h]) - __expf(lq2[h] * lk2[h]) + LAMBDA_INIT;
#pragma unroll
        for (int t = 0; t < 2; ++t) {
#pragma unroll
            for (int r = 0; r < 4; ++r) {
                O1[t][r] += src[(t * 8 + r) * 64 + lane];
                O2[t][r] += src[(t * 8 + 4 + r) * 64 + lane];
            }
            const float L1 = lbuf[qh * 4][0][t][l15] + lbuf[qh * 4 + 1][0][t][l15]
                           + lbuf[qh * 4 + 2][0][t][l15] + lbuf[qh * 4 + 3][0][t][l15];
            const float L2 = lbuf[qh * 4][1][t][l15] + lbuf[qh * 4 + 1][1][t][l15]
                           + lbuf[qh * 4 + 2][1][t][l15] + lbuf[qh * 4 + 3][1][t][l15];
            const float inv1 = 1.f / L1;
            const float inv2 = lam / L2;
            const size_t row = (size_t)(b * 2048 + qt * 64 + (qh * 2 + t) * 16 + l15) * 512
                             + h * 64;
#pragma unroll
            for (int tr = 0; tr < 4; ++tr)
#pragma unroll
                for (int r = 0; r < 4; ++r) {
                    const float val = O1[t][tr][r] * inv1 - O2[t][tr][r] * inv2;
                    ssum += val;
                    ssq += val * val;
                    o[row + tr * 16 + quad * 4 + r] = (bf16)val;
                }
        }
    }
#pragma unroll
    for (int off = 1; off < 64; off <<= 1) {
        ssum += __shfl_xor(ssum, off, 64);
        ssq += __shfl_xor(ssq, off, 64);
    }
    if (kq == 0 && lane == 0) { sred[qh][0] = ssum; sred[qh][1] = ssq; }
    __syncthreads();
    if (tid == 0) {
        const int bg = b * 4 + (h >> 1);
        atomicAdd(&stats[bg * 2],     sred[0][0] + sred[1][0]);
        atomicAdd(&stats[bg * 2 + 1], sred[0][1] + sred[1][1]);
    }
}

// ---------------------------------------------------------------------------
// Kernel 3: prep (stats-independent) + stats zeroing (replaces memset):
//   ow_g[n,c] = ow[n,c] * gnw[c]   (bf16)
//   S0[n]     = sum_c gnb[c] * ow[n,c]
// ---------------------------------------------------------------------------
__global__ __launch_bounds__(256) void prep_kernel(
    const float* __restrict__ ow, const float* __restrict__ gnw,
    const float* __restrict__ gnb, bf16* __restrict__ owg,
    float* __restrict__ S0, float* __restrict__ stats)
{
    __shared__ float red[4];
    const int tid = threadIdx.x;
    if (blockIdx.x == 0 && tid < 16) stats[tid] = 0.f;

    const int n0 = blockIdx.x * 16;
    const int c0 = tid, c1 = tid + 256;

    const float gw0 = gnw[c0], gw1 = gnw[c1];
    const float gb0 = gnb[c0], gb1 = gnb[c1];

    for (int n = 0; n < 16; ++n) {
        const size_t rowb = (size_t)(n0 + n) * 512;
        const float w0 = ow[rowb + c0];
        const float w1 = ow[rowb + c1];
        owg[rowb + c0] = (bf16)(w0 * gw0);
        owg[rowb + c1] = (bf16)(w1 * gw1);
        float s = gb0 * w0 + gb1 * w1;
#pragma unroll
        for (int off = 1; off < 64; off <<= 1) s += __shfl_xor(s, off, 64);
        if ((tid & 63) == 0) red[tid >> 6] = s;
        __syncthreads();
        if (tid == 0) S0[n0 + n] = red[0] + red[1] + red[2] + red[3];
        __syncthreads();
    }
}

// ---------------------------------------------------------------------------
// Kernel 4: output GEMM with GN folded algebraically. [unchanged from r10]
// ---------------------------------------------------------------------------
__global__ __launch_bounds__(256) void out_gemm_kernel(
    const bf16* __restrict__ o, const bf16* __restrict__ owg,
    const float* __restrict__ S0, const float* __restrict__ stats,
    const float* __restrict__ ob, float* __restrict__ y)
{
    __shared__ __align__(16) bf16 As[64 * 32];   // 4 KB
    __shared__ __align__(16) bf16 Bs[64 * 32];   // 4 KB

    const int tid = threadIdx.x;
    const int wave = tid >> 6, lane = tid & 63;
    const int l15 = lane & 15, quad = lane >> 4;

    const int mb = blockIdx.x >> 3;
    const int nb = blockIdx.x & 7;
    const int b = mb >> 5;

    const float N = 128.f * 2048.f;
    float mu[4], rs[4];
#pragma unroll
    for (int g = 0; g < 4; ++g) {
        const float m = stats[(b * 4 + g) * 2] / N;
        const float var = stats[(b * 4 + g) * 2 + 1] / N - m * m;
        mu[g] = m;
        rs[g] = rsqrtf(var + EPS);
    }

    const int srow = wave * 16 + (lane >> 2);
    const int scol = (lane & 3) * 8;
    const bf16* ag = o + (size_t)(mb * 64 + srow) * 512 + scol;
    const bf16* bg = owg + (size_t)(nb * 64 + srow) * 512 + scol;
    bf16* adst = As + wave * 512;
    bf16* bdst = Bs + wave * 512;

    f32x4 acc[4], tot[4];
#pragma unroll
    for (int i = 0; i < 4; ++i) {
        acc[i] = (f32x4){0.f, 0.f, 0.f, 0.f};
        tot[i] = (f32x4){0.f, 0.f, 0.f, 0.f};
    }
    float s1g[4];
    float s1p = 0.f;
#pragma unroll
    for (int g = 0; g < 4; ++g) s1g[g] = 0.f;

    for (int kk = 0; kk < 16; ++kk) {
        gload_lds16(ag + kk * 32, adst);
        gload_lds16(bg + kk * 32, bdst);
        __syncthreads();

        bf16x8 af[4];
#pragma unroll
        for (int i = 0; i < 4; ++i)
            af[i] = *(const bf16x8*)(As + (i * 16 + l15) * 32 + quad * 8);
        const bf16x8 bf = *(const bf16x8*)(Bs + (wave * 16 + l15) * 32 + quad * 8);

#pragma unroll
        for (int i = 0; i < 4; ++i)
            acc[i] = MFMA16(af[i], bf, acc[i]);

#pragma unroll
        for (int j = 0; j < 8; ++j) s1p += (float)bf[j];

        __syncthreads();

        if ((kk & 3) == 3) {
            const int g = kk >> 2;
#pragma unroll
            for (int i = 0; i < 4; ++i) {
#pragma unroll
                for (int r = 0; r < 4; ++r) tot[i][r] += rs[g] * acc[i][r];
                acc[i] = (f32x4){0.f, 0.f, 0.f, 0.f};
            }
            float sg = s1p + __shfl_xor(s1p, 16, 64);
            sg += __shfl_xor(sg, 32, 64);
            s1g[g] = sg;
            s1p = 0.f;
        }
    }

    const int ncol = nb * 64 + wave * 16 + l15;
    float bias = S0[ncol] + ob[ncol];
#pragma unroll
    for (int g = 0; g < 4; ++g) bias -= mu[g] * rs[g] * s1g[g];

#pragma unroll
    for (int i = 0; i < 4; ++i) {
#pragma unroll
        for (int r = 0; r < 4; ++r) {
            const int m = mb * 64 + i * 16 + quad * 4 + r;
            y[(size_t)m * 512 + ncol] = tot[i][r] + bias;
        }
    }
}

// ---------------------------------------------------------------------------
extern "C" void kernel_launch(void* const* d_in, const int* in_sizes, int n_in,
                              void* d_out, int out_size, void* d_ws, size_t ws_size,
                              hipStream_t stream)
{
    const float* x   = (const float*)d_in[0];
    const float* K1w = (const float*)d_in[1];
    const float* K1b = (const float*)d_in[2];
    const float* Q1w = (const float*)d_in[3];
    const float* K2w = (const float*)d_in[4];
    const float* K2b = (const float*)d_in[5];
    const float* Q2w = (const float*)d_in[6];
    const float* Vw  = (const float*)d_in[7];
    const float* lq1 = (const float*)d_in[8];
    const float* lk1 = (const float*)d_in[9];
    const float* lq2 = (const float*)d_in[10];
    const float* lk2 = (const float*)d_in[11];
    const float* gnw = (const float*)d_in[12];
    const float* gnb = (const float*)d_in[13];
    const float* Ow  = (const float*)d_in[14];
    const float* Ob  = (const float*)d_in[15];

    const size_t SZ = (size_t)2 * 8 * 2048 * 64;   // 2M elements per tensor
    bf16* q1 = (bf16*)d_ws;
    bf16* k1 = q1 + SZ;
    bf16* q2 = k1 + SZ;
    bf16* k2 = q2 + SZ;
    bf16* vt = k2 + SZ;
    bf16* o  = vt + SZ;
    bf16* owg = o + SZ;                       // 512x512 bf16 (0.5 MB)
    float* S0 = (float*)(owg + 512 * 512);    // 512 f32
    float* stats = S0 + 512;                  // 16 f32

    proj_kernel<<<640, 256, 0, stream>>>(x, Q1w, K1w, Q2w, K2w, Vw, K1b, K2b,
                                         q1, k1, q2, k2, vt);
    prep_kernel<<<32, 256, 0, stream>>>(Ow, gnw, gnb, owg, S0, stats);
    attn_kernel<<<512, 512, 0, stream>>>(q1, k1, q2, k2, vt,
                                         lq1, lk1, lq2, lk2, o, stats);
    out_gemm_kernel<<<512, 256, 0, stream>>>(o, owg, S0, stats, Ob,
                                             (float*)d_out);
}

// Round 12
// 190.188 us; speedup vs baseline: 1.1485x; 1.1485x over previous
//
#include <hip/hip_runtime.h>
#include <hip/hip_bf16.h>

typedef __bf16 bf16;
typedef __attribute__((ext_vector_type(8))) __bf16 bf16x8;
typedef __attribute__((ext_vector_type(4))) float f32x4;

#define MFMA16(a, b, c) __builtin_amdgcn_mfma_f32_16x16x32_bf16((a), (b), (c), 0, 0, 0)

// B=2, S=2048, D=512, H=8, hd=64, G=4. All I/O float32; bf16 MFMA compute.
static constexpr float EPS = 1e-5f;
static constexpr float LAMBDA_INIT = 0.2f;

// Load 8 consecutive f32 (32B, 16B-aligned) and convert to bf16x8.
__device__ __forceinline__ bf16x8 cvt8(const float* p) {
    const f32x4 a = *(const f32x4*)p;
    const f32x4 b = *(const f32x4*)(p + 4);
    bf16x8 r;
    r[0] = (bf16)a[0]; r[1] = (bf16)a[1]; r[2] = (bf16)a[2]; r[3] = (bf16)a[3];
    r[4] = (bf16)b[0]; r[5] = (bf16)b[1]; r[6] = (bf16)b[2]; r[7] = (bf16)b[3];
    return r;
}

// Async 16B global -> LDS (lane i lands at lds_base + i*16; base wave-uniform).
__device__ __forceinline__ void gload_lds16(const void* g, void* l) {
    __builtin_amdgcn_global_load_lds(
        (const __attribute__((address_space(1))) unsigned int*)g,
        (__attribute__((address_space(3))) unsigned int*)l,
        16, 0, 0);
}

// ---------------------------------------------------------------------------
// Kernel 1: combined cvt + prep.
// Blocks [0, 1664): convert x -> xb (bf16) and the 5 weights -> wb
//   (concat [Q1|K1|Q2|K2|V], bf16).
// Blocks [1664, 1696): prep for GN-folded out_gemm:
//   owg[n,c] = ow[n,c]*gnw[c] (bf16); S0[n] = sum_c gnb[c]*ow[n,c];
//   block 1664 also zeroes stats.
// ---------------------------------------------------------------------------
__global__ __launch_bounds__(256) void prep_kernel(
    const float* __restrict__ x,
    const float* __restrict__ q1w, const float* __restrict__ k1w,
    const float* __restrict__ q2w, const float* __restrict__ k2w,
    const float* __restrict__ vw,
    const float* __restrict__ ow, const float* __restrict__ gnw,
    const float* __restrict__ gnb,
    bf16* __restrict__ xb, bf16* __restrict__ wb,
    bf16* __restrict__ owg, float* __restrict__ S0, float* __restrict__ stats)
{
    const int tid = threadIdx.x;
    if (blockIdx.x < 1664) {
        const size_t base = ((size_t)blockIdx.x * 256 + tid) * 8;
        if (base < 2097152) {                    // x: 2*2048*512
            *(bf16x8*)(xb + base) = cvt8(x + base);
        } else {
            const size_t wbase = base - 2097152; // 0..1310720 (5 x 262144)
            const int wsel = (int)(wbase >> 18);
            const size_t off = wbase & 262143;
            const float* W = (wsel == 0) ? q1w : (wsel == 1) ? k1w :
                             (wsel == 2) ? q2w : (wsel == 3) ? k2w : vw;
            *(bf16x8*)(wb + wbase) = cvt8(W + off);
        }
        return;
    }

    __shared__ float red[4];
    const int pb = blockIdx.x - 1664;            // 0..31
    if (pb == 0 && tid < 16) stats[tid] = 0.f;

    const int n0 = pb * 16;
    const int c0 = tid, c1 = tid + 256;
    const float gw0 = gnw[c0], gw1 = gnw[c1];
    const float gb0 = gnb[c0], gb1 = gnb[c1];

    for (int n = 0; n < 16; ++n) {
        const size_t rowb = (size_t)(n0 + n) * 512;
        const float w0 = ow[rowb + c0];
        const float w1 = ow[rowb + c1];
        owg[rowb + c0] = (bf16)(w0 * gw0);
        owg[rowb + c1] = (bf16)(w1 * gw1);
        float s = gb0 * w0 + gb1 * w1;
#pragma unroll
        for (int off = 1; off < 64; off <<= 1) s += __shfl_xor(s, off, 64);
        if ((tid & 63) == 0) red[tid >> 6] = s;
        __syncthreads();
        if (tid == 0) S0[n0 + n] = red[0] + red[1] + red[2] + red[3];
        __syncthreads();
    }
}

// ---------------------------------------------------------------------------
// Kernel 2: fused QKV projection GEMM, pure bf16 (xb @ wb^T).
// 128x128 tile (4 waves x 64x64), BK=32, 16 KB LDS staged via
// global_load_lds(16B); no in-loop cvt. Epilogue unchanged (verified):
// q1/q2 scaled 0.125; V^T stored with the period-32 key permutation.
// ---------------------------------------------------------------------------
__global__ __launch_bounds__(256) void proj_kernel(
    const bf16* __restrict__ xb, const bf16* __restrict__ wb,
    const float* __restrict__ k1b, const float* __restrict__ k2b,
    bf16* __restrict__ q1o, bf16* __restrict__ k1o,
    bf16* __restrict__ q2o, bf16* __restrict__ k2o,
    bf16* __restrict__ vto)
{
    __shared__ __align__(16) bf16 As[128 * 32];   // 8 KB
    __shared__ __align__(16) bf16 Bs[128 * 32];   // 8 KB

    const int tid = threadIdx.x;
    const int wave = tid >> 6, lane = tid & 63;
    const int l15 = lane & 15, quad = lane >> 4;
    const int wm = wave >> 1, wn = wave & 1;

    const int mb = blockIdx.x / 20;
    const int nb = blockIdx.x % 20;
    const int wsel = nb >> 2;
    const int nrow0 = (nb & 3) * 128;

    // Staging: 8 chunks/tensor (16 rows x 32 bf16 = 1 KB); wave stages 2+2.
    const int srow = lane >> 2;                   // 0..15 row within chunk
    const int scol = (lane & 3) * 8;              // bf16 col within 32
    const bf16* ag = xb + (size_t)(mb * 128 + srow) * 512 + scol;
    const bf16* bg = wb + (size_t)(wsel * 512 + nrow0 + srow) * 512 + scol;

    f32x4 acc[4][4];
#pragma unroll
    for (int i = 0; i < 4; ++i)
#pragma unroll
        for (int j = 0; j < 4; ++j)
            acc[i][j] = (f32x4){0.f, 0.f, 0.f, 0.f};

    for (int k0 = 0; k0 < 512; k0 += 32) {
#pragma unroll
        for (int c = 0; c < 2; ++c) {
            const int chunk = wave * 2 + c;       // 0..7
            gload_lds16(ag + (size_t)(chunk * 16) * 512 + k0, As + chunk * 512);
            gload_lds16(bg + (size_t)(chunk * 16) * 512 + k0, Bs + chunk * 512);
        }
        __syncthreads();                          // drains vmcnt before use

        bf16x8 af[4], bfr[4];
#pragma unroll
        for (int i = 0; i < 4; ++i)
            af[i] = *(const bf16x8*)(As + (wm * 64 + i * 16 + l15) * 32 + quad * 8);
#pragma unroll
        for (int j = 0; j < 4; ++j)
            bfr[j] = *(const bf16x8*)(Bs + (wn * 64 + j * 16 + l15) * 32 + quad * 8);

#pragma unroll
        for (int i = 0; i < 4; ++i)
#pragma unroll
            for (int j = 0; j < 4; ++j)
                acc[i][j] = MFMA16(af[i], bfr[j], acc[i][j]);

        __syncthreads();                          // before next stage overwrite
    }

    const float scale = (wsel == 0 || wsel == 2) ? 0.125f : 1.0f;
#pragma unroll
    for (int j = 0; j < 4; ++j) {
        const int ncol = nrow0 + wn * 64 + j * 16 + l15;
        float bias = 0.f;
        if (wsel == 1) bias = k1b[ncol];
        if (wsel == 3) bias = k2b[ncol];
        const int h = ncol >> 6, hd = ncol & 63;
#pragma unroll
        for (int i = 0; i < 4; ++i) {
#pragma unroll
            for (int r = 0; r < 4; ++r) {
                const int m = mb * 128 + wm * 64 + i * 16 + quad * 4 + r;
                const int bidx = m >> 11, s = m & 2047;
                const float v = acc[i][j][r] * scale + bias;
                if (wsel == 4) {
                    const int s5 = s & 31;
                    const int p = ((s5 & 15) >> 2) * 8 + (s5 & 3) + ((s5 >> 4) << 2);
                    const int sp = (s & ~31) | p;
                    vto[((size_t)(bidx * 8 + h) * 64 + hd) * 2048 + sp] = (bf16)v;
                } else {
                    bf16* dst = (wsel == 0) ? q1o : (wsel == 1) ? k1o :
                                (wsel == 2) ? q2o : k2o;
                    dst[((size_t)(bidx * 8 + h) * 2048 + s) * 64 + hd] = (bf16)v;
                }
            }
        }
    }
}

// ---------------------------------------------------------------------------
// Kernel 3: dual-stream flash attention + fused GroupNorm partial stats.
// [reverted to round-10 version: 58 us measured]
// ---------------------------------------------------------------------------
__global__ __launch_bounds__(512, 4) void attn_kernel(
    const bf16* __restrict__ q1, const bf16* __restrict__ k1,
    const bf16* __restrict__ q2, const bf16* __restrict__ k2,
    const bf16* __restrict__ vt,
    const float* __restrict__ lq1, const float* __restrict__ lk1,
    const float* __restrict__ lq2, const float* __restrict__ lk2,
    bf16* __restrict__ o, float* __restrict__ stats)
{
    __shared__ __align__(16) bf16 smem[12288];   // 24 KB: K1 | K2 | V
    __shared__ float lbuf[8][2][16];
    __shared__ float sred[8][2];

    const int tid = threadIdx.x;
    const int wave = tid >> 6;
    const int lane = tid & 63;
    const int l15 = lane & 15, quad = lane >> 4;
    const int qtile = wave & 3;
    const int kg = wave >> 2;

    const int bh = blockIdx.x >> 5;
    const int qt = blockIdx.x & 31;
    const int b = bh >> 3, h = bh & 7;

    const bf16* k1t = k1 + (size_t)bh * 2048 * 64;
    const bf16* k2t = k2 + (size_t)bh * 2048 * 64;
    const bf16* vtt = vt + (size_t)bh * 64 * 2048;

    const int qrow = qt * 64 + qtile * 16 + l15;
    const bf16* q1p = q1 + ((size_t)bh * 2048 + qrow) * 64 + quad * 8;
    const bf16* q2p = q2 + ((size_t)bh * 2048 + qrow) * 64 + quad * 8;
    const bf16x8 q1f0 = *(const bf16x8*)(q1p);
    const bf16x8 q1f1 = *(const bf16x8*)(q1p + 32);
    const bf16x8 q2f0 = *(const bf16x8*)(q2p);
    const bf16x8 q2f1 = *(const bf16x8*)(q2p + 32);

    const int sw = wave & 3;
    const int skey0 = (wave < 4) ? 0 : 1024;
    bf16* k1dst = smem + wave * 512;
    bf16* k2dst = smem + 4096 + wave * 512;
    bf16* vdst  = smem + 8192 + wave * 512;
    const size_t ksrc0 = (size_t)(skey0 + sw * 8 + (lane >> 3)) * 64
                       + 8 * ((lane & 7) ^ (lane >> 3));
    const size_t vsrc0 = (size_t)(sw * 16 + (lane >> 2)) * 2048 + skey0 + (lane & 3) * 8;

    const bf16* k1r = smem + kg * 2048;
    const bf16* k2r = smem + 4096 + kg * 2048;
    const bf16* vr  = smem + 8192 + kg * 2048;

    const int koffa = 8 * (quad ^ (l15 & 7));
    const int koffb = 8 * ((quad + 4) ^ (l15 & 7));

    f32x4 O1[4], O2[4];
    float l1 = 0.f, l2 = 0.f;
#pragma unroll
    for (int t = 0; t < 4; ++t) {
        O1[t] = (f32x4){0.f, 0.f, 0.f, 0.f};
        O2[t] = (f32x4){0.f, 0.f, 0.f, 0.f};
    }

    for (int it = 0; it < 32; ++it) {
        const size_t koff = ksrc0 + (size_t)it * 32 * 64;
        gload_lds16(k1t + koff, k1dst);
        gload_lds16(k2t + koff, k2dst);
        gload_lds16(vtt + vsrc0 + it * 32, vdst);
        __syncthreads();

        const bf16x8 k1t0a = *(const bf16x8*)(k1r + l15 * 64 + koffa);
        const bf16x8 k1t0b = *(const bf16x8*)(k1r + l15 * 64 + koffb);
        const bf16x8 k1t1a = *(const bf16x8*)(k1r + (16 + l15) * 64 + koffa);
        const bf16x8 k1t1b = *(const bf16x8*)(k1r + (16 + l15) * 64 + koffb);
        const bf16x8 k2t0a = *(const bf16x8*)(k2r + l15 * 64 + koffa);
        const bf16x8 k2t0b = *(const bf16x8*)(k2r + l15 * 64 + koffb);
        const bf16x8 k2t1a = *(const bf16x8*)(k2r + (16 + l15) * 64 + koffa);
        const bf16x8 k2t1b = *(const bf16x8*)(k2r + (16 + l15) * 64 + koffb);
        const bf16x8 v0 = *(const bf16x8*)(vr + l15 * 32 + quad * 8);
        const bf16x8 v1 = *(const bf16x8*)(vr + (16 + l15) * 32 + quad * 8);
        const bf16x8 v2 = *(const bf16x8*)(vr + (32 + l15) * 32 + quad * 8);
        const bf16x8 v3 = *(const bf16x8*)(vr + (48 + l15) * 32 + quad * 8);

        f32x4 z = (f32x4){0.f, 0.f, 0.f, 0.f};
        f32x4 s1t0 = MFMA16(k1t0a, q1f0, z);  s1t0 = MFMA16(k1t0b, q1f1, s1t0);
        f32x4 s1t1 = MFMA16(k1t1a, q1f0, z);  s1t1 = MFMA16(k1t1b, q1f1, s1t1);
        f32x4 s2t0 = MFMA16(k2t0a, q2f0, z);  s2t0 = MFMA16(k2t0b, q2f1, s2t0);
        f32x4 s2t1 = MFMA16(k2t1a, q2f0, z);  s2t1 = MFMA16(k2t1b, q2f1, s2t1);

        bf16x8 b1, b2;
#pragma unroll
        for (int r = 0; r < 4; ++r) {
            float e;
            e = __expf(s1t0[r]); l1 += e; b1[r]     = (bf16)e;
            e = __expf(s1t1[r]); l1 += e; b1[4 + r] = (bf16)e;
            e = __expf(s2t0[r]); l2 += e; b2[r]     = (bf16)e;
            e = __expf(s2t1[r]); l2 += e; b2[4 + r] = (bf16)e;
        }

        O1[0] = MFMA16(v0, b1, O1[0]);
        O1[1] = MFMA16(v1, b1, O1[1]);
        O1[2] = MFMA16(v2, b1, O1[2]);
        O1[3] = MFMA16(v3, b1, O1[3]);
        O2[0] = MFMA16(v0, b2, O2[0]);
        O2[1] = MFMA16(v1, b2, O2[1]);
        O2[2] = MFMA16(v2, b2, O2[2]);
        O2[3] = MFMA16(v3, b2, O2[3]);

        __syncthreads();
    }

    l1 += __shfl_xor(l1, 16, 64);  l1 += __shfl_xor(l1, 32, 64);
    l2 += __shfl_xor(l2, 16, 64);  l2 += __shfl_xor(l2, 32, 64);
    if (lane < 16) {
        lbuf[wave][0][lane] = l1;
        lbuf[wave][1][lane] = l2;
    }
    __syncthreads();

    f32x4* rb = (f32x4*)smem;
    if (wave == 4 || wave == 5) {
        f32x4* dst = rb + (wave - 4) * 512;
#pragma unroll
        for (int t = 0; t < 4; ++t) {
            dst[t * 64 + lane]       = O1[t];
            dst[(4 + t) * 64 + lane] = O2[t];
        }
    }
    __syncthreads();
    if (wave == 0 || wave == 1) {
        const f32x4* src = rb + wave * 512;
#pragma unroll
        for (int t = 0; t < 4; ++t) {
            O1[t] += src[t * 64 + lane];
            O2[t] += src[(4 + t) * 64 + lane];
        }
    }
    __syncthreads();
    if (wave == 6 || wave == 7) {
        f32x4* dst = rb + (wave - 6) * 512;
#pragma unroll
        for (int t = 0; t < 4; ++t) {
            dst[t * 64 + lane]       = O1[t];
            dst[(4 + t) * 64 + lane] = O2[t];
        }
    }
    __syncthreads();
    if (wave == 2 || wave == 3) {
        const f32x4* src = rb + (wave - 2) * 512;
#pragma unroll
        for (int t = 0; t < 4; ++t) {
            O1[t] += src[t * 64 + lane];
            O2[t] += src[(4 + t) * 64 + lane];
        }
    }

    float ssum = 0.f, ssq = 0.f;
    if (wave < 4) {
        const float L1 = l1 + lbuf[wave + 4][0][l15];
        const float L2 = l2 + lbuf[wave + 4][1][l15];
        const float lam = __expf(lq1[h] * lk1[h]) - __expf(lq2[h] * lk2[h]) + LAMBDA_INIT;
        const float inv1 = 1.f / L1;
        const float inv2 = lam / L2;
        const size_t row = (size_t)(b * 2048 + qt * 64 + wave * 16 + l15) * 512 + h * 64;
#pragma unroll
        for (int t = 0; t < 4; ++t) {
#pragma unroll
            for (int r = 0; r < 4; ++r) {
                const float val = O1[t][r] * inv1 - O2[t][r] * inv2;
                ssum += val;
                ssq += val * val;
                o[row + t * 16 + quad * 4 + r] = (bf16)val;
            }
        }
    }
#pragma unroll
    for (int off = 1; off < 64; off <<= 1) {
        ssum += __shfl_xor(ssum, off, 64);
        ssq += __shfl_xor(ssq, off, 64);
    }
    if (lane == 0) { sred[wave][0] = ssum; sred[wave][1] = ssq; }
    __syncthreads();
    if (tid == 0) {
        float s0 = 0.f, s1 = 0.f;
        for (int w = 0; w < 8; ++w) { s0 += sred[w][0]; s1 += sred[w][1]; }
        const int bg = b * 4 + (h >> 1);
        atomicAdd(&stats[bg * 2], s0);
        atomicAdd(&stats[bg * 2 + 1], s1);
    }
}

// ---------------------------------------------------------------------------
// Kernel 4: output GEMM with GN folded algebraically. [unchanged from r10]
// ---------------------------------------------------------------------------
__global__ __launch_bounds__(256) void out_gemm_kernel(
    const bf16* __restrict__ o, const bf16* __restrict__ owg,
    const float* __restrict__ S0, const float* __restrict__ stats,
    const float* __restrict__ ob, float* __restrict__ y)
{
    __shared__ __align__(16) bf16 As[64 * 32];   // 4 KB
    __shared__ __align__(16) bf16 Bs[64 * 32];   // 4 KB

    const int tid = threadIdx.x;
    const int wave = tid >> 6, lane = tid & 63;
    const int l15 = lane & 15, quad = lane >> 4;

    const int mb = blockIdx.x >> 3;
    const int nb = blockIdx.x & 7;
    const int b = mb >> 5;

    const float N = 128.f * 2048.f;
    float mu[4], rs[4];
#pragma unroll
    for (int g = 0; g < 4; ++g) {
        const float m = stats[(b * 4 + g) * 2] / N;
        const float var = stats[(b * 4 + g) * 2 + 1] / N - m * m;
        mu[g] = m;
        rs[g] = rsqrtf(var + EPS);
    }

    const int srow = wave * 16 + (lane >> 2);
    const int scol = (lane & 3) * 8;
    const bf16* ag = o + (size_t)(mb * 64 + srow) * 512 + scol;
    const bf16* bg = owg + (size_t)(nb * 64 + srow) * 512 + scol;
    bf16* adst = As + wave * 512;
    bf16* bdst = Bs + wave * 512;

    f32x4 acc[4], tot[4];
#pragma unroll
    for (int i = 0; i < 4; ++i) {
        acc[i] = (f32x4){0.f, 0.f, 0.f, 0.f};
        tot[i] = (f32x4){0.f, 0.f, 0.f, 0.f};
    }
    float s1g[4];
    float s1p = 0.f;
#pragma unroll
    for (int g = 0; g < 4; ++g) s1g[g] = 0.f;

    for (int kk = 0; kk < 16; ++kk) {
        gload_lds16(ag + kk * 32, adst);
        gload_lds16(bg + kk * 32, bdst);
        __syncthreads();

        bf16x8 af[4];
#pragma unroll
        for (int i = 0; i < 4; ++i)
            af[i] = *(const bf16x8*)(As + (i * 16 + l15) * 32 + quad * 8);
        const bf16x8 bf = *(const bf16x8*)(Bs + (wave * 16 + l15) * 32 + quad * 8);

#pragma unroll
        for (int i = 0; i < 4; ++i)
            acc[i] = MFMA16(af[i], bf, acc[i]);

#pragma unroll
        for (int j = 0; j < 8; ++j) s1p += (float)bf[j];

        __syncthreads();

        if ((kk & 3) == 3) {
            const int g = kk >> 2;
#pragma unroll
            for (int i = 0; i < 4; ++i) {
#pragma unroll
                for (int r = 0; r < 4; ++r) tot[i][r] += rs[g] * acc[i][r];
                acc[i] = (f32x4){0.f, 0.f, 0.f, 0.f};
            }
            float sg = s1p + __shfl_xor(s1p, 16, 64);
            sg += __shfl_xor(sg, 32, 64);
            s1g[g] = sg;
            s1p = 0.f;
        }
    }

    const int ncol = nb * 64 + wave * 16 + l15;
    float bias = S0[ncol] + ob[ncol];
#pragma unroll
    for (int g = 0; g < 4; ++g) bias -= mu[g] * rs[g] * s1g[g];

#pragma unroll
    for (int i = 0; i < 4; ++i) {
#pragma unroll
        for (int r = 0; r < 4; ++r) {
            const int m = mb * 64 + i * 16 + quad * 4 + r;
            y[(size_t)m * 512 + ncol] = tot[i][r] + bias;
        }
    }
}

// ---------------------------------------------------------------------------
extern "C" void kernel_launch(void* const* d_in, const int* in_sizes, int n_in,
                              void* d_out, int out_size, void* d_ws, size_t ws_size,
                              hipStream_t stream)
{
    const float* x   = (const float*)d_in[0];
    const float* K1w = (const float*)d_in[1];
    const float* K1b = (const float*)d_in[2];
    const float* Q1w = (const float*)d_in[3];
    const float* K2w = (const float*)d_in[4];
    const float* K2b = (const float*)d_in[5];
    const float* Q2w = (const float*)d_in[6];
    const float* Vw  = (const float*)d_in[7];
    const float* lq1 = (const float*)d_in[8];
    const float* lk1 = (const float*)d_in[9];
    const float* lq2 = (const float*)d_in[10];
    const float* lk2 = (const float*)d_in[11];
    const float* gnw = (const float*)d_in[12];
    const float* gnb = (const float*)d_in[13];
    const float* Ow  = (const float*)d_in[14];
    const float* Ob  = (const float*)d_in[15];

    const size_t SZ = (size_t)2 * 8 * 2048 * 64;   // 2M elements per tensor
    bf16* q1 = (bf16*)d_ws;
    bf16* k1 = q1 + SZ;
    bf16* q2 = k1 + SZ;
    bf16* k2 = q2 + SZ;
    bf16* vt = k2 + SZ;
    bf16* o  = vt + SZ;                 // attn output; slot shared with xb
    bf16* xb = o;                       // x bf16 (2M elems) — dead before attn writes o
    bf16* wb = o + SZ;                  // 2560x512 bf16 (2.6 MB)
    bf16* owg = wb + (size_t)2560 * 512;
    float* S0 = (float*)(owg + 512 * 512);
    float* stats = S0 + 512;

    prep_kernel<<<1696, 256, 0, stream>>>(x, Q1w, K1w, Q2w, K2w, Vw,
                                          Ow, gnw, gnb, xb, wb, owg, S0, stats);
    proj_kernel<<<640, 256, 0, stream>>>(xb, wb, K1b, K2b,
                                         q1, k1, q2, k2, vt);
    attn_kernel<<<512, 512, 0, stream>>>(q1, k1, q2, k2, vt,
                                         lq1, lk1, lq2, lk2, o, stats);
    out_gemm_kernel<<<512, 256, 0, stream>>>(o, owg, S0, stats, Ob,
                                             (float*)d_out);
}